// Round 9
// baseline (116.891 us; speedup 1.0000x reference)
//
#include <hip/hip_runtime.h>

typedef __bf16 bf16;
typedef __attribute__((ext_vector_type(4))) bf16 bf16x4;
typedef __attribute__((ext_vector_type(8))) bf16 bf16x8;
typedef __attribute__((ext_vector_type(4))) float f32x4;

#define MFMA16(a, b, c) __builtin_amdgcn_mfma_f32_16x16x32_bf16(a, b, c, 0, 0, 0)

#define GLDS16(gsrc, ldst) __builtin_amdgcn_global_load_lds(                   \
    (const __attribute__((address_space(1))) unsigned int*)(gsrc),             \
    (__attribute__((address_space(3))) unsigned int*)(ldst), 16, 0, 0)

#define WAITVM(N) asm volatile("s_waitcnt vmcnt(" #N ")" ::: "memory")

constexpr int Bb = 4, Ss = 4096, Ee = 1024, Hh = 128;
constexpr int Mrows = Bb * Ss;  // 16384
constexpr int QB = 128;         // attn q-block
constexpr int NQB = Ss / QB;    // 32

// ---------------------------------------------------------------------------
// Kernel 0: W prep. Transpose W [E,H] f32 -> Wt [3][H][E] bf16.
// grid (E/16, 3), block 256.
// ---------------------------------------------------------------------------
__global__ __launch_bounds__(256) void wprep_kernel(
    const float* __restrict__ Wq, const float* __restrict__ Wk,
    const float* __restrict__ Wv, bf16* __restrict__ Wt)
{
    __shared__ bf16 Sb[16][136];
    const int w = blockIdx.y;
    const float* W = (w == 0) ? Wq : (w == 1) ? Wk : Wv;
    const int k0 = blockIdx.x * 16;
    const int t = threadIdx.x;
    {
        int r = t >> 4, cg = (t & 15) * 8;
        const float4* src = (const float4*)(W + (size_t)(k0 + r) * Hh + cg);
        float4 v0 = src[0], v1 = src[1];
        bf16x4 o0, o1;
        o0[0] = (bf16)v0.x; o0[1] = (bf16)v0.y; o0[2] = (bf16)v0.z; o0[3] = (bf16)v0.w;
        o1[0] = (bf16)v1.x; o1[1] = (bf16)v1.y; o1[2] = (bf16)v1.z; o1[3] = (bf16)v1.w;
        *(bf16x4*)&Sb[r][cg] = o0;
        *(bf16x4*)&Sb[r][cg + 4] = o1;
    }
    __syncthreads();
    {
        int h = t >> 1, kseg = (t & 1) * 8;
        bf16x8 v;
        #pragma unroll
        for (int e = 0; e < 8; ++e) v[e] = Sb[kseg + e][h];
        *(bf16x8*)&Wt[((size_t)w * Hh + h) * Ee + k0 + kseg] = v;
    }
}

// ---------------------------------------------------------------------------
// Kernel 1: fused QKV projection — double-buffered gl_lds + counted vmcnt.
// grid (Mrows/32) = 512 (2 blocks/CU @ 56KB), block 256 (4 waves).
// Block: 32 rows x 384 cols, BK=32, 32 k-tiles. Per k-tile per wave:
// 7 gl_lds (1 A from HBM, 6 B from L2-resident Wt; each wave stages exactly
// the B rows it reads), s_waitcnt vmcnt(7) keeps next tile's loads in
// flight across the barrier (T3/T4). Both-sides XOR swizzle, linear dests.
// Wave w owns col-frags F = 6w..6w+5 (F>>3 = proj, (F&7)*16 = col).
// V written transposed: Vtg[b][h][s]. Q pre-scaled by 1/sqrt(H).
// ---------------------------------------------------------------------------
__global__ __launch_bounds__(256, 2) void proj_kernel(
    const float* __restrict__ embds, const bf16* __restrict__ Wt,
    const float* __restrict__ bq, const float* __restrict__ bk,
    const float* __restrict__ bv,
    bf16* __restrict__ Qb, bf16* __restrict__ Kb, bf16* __restrict__ Vtg)
{
    // per buffer: A = 32 rows x 128B (f32, swizzled chunks) = 4096B
    //             B = 384 rows x 64B (bf16, swizzled chunks) = 24576B
    __shared__ char LB[2][28672];

    const int t = threadIdx.x;
    const int wv = t >> 6, lane = t & 63, lo = lane & 15, hi = lane >> 4;
    const int m0 = blockIdx.x * 32;

    f32x4 acc[2][6];
    #pragma unroll
    for (int rg = 0; rg < 2; ++rg)
        #pragma unroll
        for (int f = 0; f < 6; ++f) acc[rg][f] = f32x4{0.f, 0.f, 0.f, 0.f};

    // ---- staging sources (per lane, pre-swizzled) / dests (linear) ----
    // A: wave wv stages rows 8wv..8wv+7; lane -> row 8wv+(lane>>3),
    //    LDS chunk lane&7 holds source chunk (lane&7)^(row&7).
    const int arow = 8 * wv + (lane >> 3);
    const float* ag = embds + (size_t)(m0 + arow) * Ee
                    + (size_t)(((lane & 7) ^ (lane >> 3)) * 4);
    char* aD = &LB[0][0] + wv * 1024;
    // B: wave wv stages rows [96wv, 96wv+96); instr j: rows 96wv+16j+(lane>>2),
    //    LDS chunk lane&3 holds source chunk (lane&3)^((r&3))^((r>>2)&3).
    const int srcB = (lane & 3) ^ ((lane >> 2) & 3) ^ (lane >> 4);
    const bf16* bg = Wt + (size_t)(96 * wv + (lane >> 2)) * Ee + srcB * 8;
    char* bD = &LB[0][0] + 4096 + wv * 6144;

#define PISSUE(K0, BUF) do {                                     \
        GLDS16(ag + (K0), aD + (BUF) * 28672);                   \
        _Pragma("unroll")                                        \
        for (int j_ = 0; j_ < 6; ++j_)                           \
            GLDS16(bg + (size_t)j_ * (16 * Ee) + (K0),           \
                   bD + (BUF) * 28672 + j_ * 1024);              \
    } while (0)

    PISSUE(0, 0);
    for (int t_ = 0; t_ < 32; ++t_) {
        const int buf = t_ & 1;
        if (t_ < 31) {
            PISSUE((t_ + 1) * 32, buf ^ 1);
            WAITVM(7);                       // tile t_ done; t_+1 in flight
        } else {
            WAITVM(0);
        }
        __builtin_amdgcn_s_barrier();
        __builtin_amdgcn_sched_barrier(0);

        const char* Lb = &LB[buf][0];
        // A fragments (f32 -> bf16), rows lo and 16+lo, k = hi*8..hi*8+7
        bf16x8 a0, a1;
        {
            const int p0 = (2 * hi) ^ (lo & 7);
            const char* ar = Lb + lo * 128;
            float4 q0 = *(const float4*)(ar + p0 * 16);
            float4 q1 = *(const float4*)(ar + (p0 ^ 1) * 16);
            a0[0] = (bf16)q0.x; a0[1] = (bf16)q0.y; a0[2] = (bf16)q0.z; a0[3] = (bf16)q0.w;
            a0[4] = (bf16)q1.x; a0[5] = (bf16)q1.y; a0[6] = (bf16)q1.z; a0[7] = (bf16)q1.w;
            const char* ar2 = Lb + (16 + lo) * 128;   // (16+lo)&7 == lo&7
            float4 r0 = *(const float4*)(ar2 + p0 * 16);
            float4 r1 = *(const float4*)(ar2 + (p0 ^ 1) * 16);
            a1[0] = (bf16)r0.x; a1[1] = (bf16)r0.y; a1[2] = (bf16)r0.z; a1[3] = (bf16)r0.w;
            a1[4] = (bf16)r1.x; a1[5] = (bf16)r1.y; a1[6] = (bf16)r1.z; a1[7] = (bf16)r1.w;
        }
        __builtin_amdgcn_s_setprio(1);
        {
            const int pos = hi ^ (lo & 3) ^ ((lo >> 2) & 3);
            #pragma unroll
            for (int f = 0; f < 6; ++f) {
                const int brow = (wv * 6 + f) * 16 + lo;
                bf16x8 b = *(const bf16x8*)(Lb + 4096 + brow * 64 + pos * 16);
                acc[0][f] = MFMA16(a0, b, acc[0][f]);
                acc[1][f] = MFMA16(a1, b, acc[1][f]);
            }
        }
        __builtin_amdgcn_s_setprio(0);
        __builtin_amdgcn_s_barrier();        // reads done before overwrite
    }
#undef PISSUE
    // epilogue: frag F -> proj/col; V transposed
    #pragma unroll
    for (int f = 0; f < 6; ++f) {
        const int F = wv * 6 + f;
        const int p = F >> 3;
        const int col = (F & 7) * 16 + lo;
        const float* bias = (p == 0) ? bq : (p == 1) ? bk : bv;
        float bvv = bias[col];
        if (p == 2) {
            const int mb = m0 >> 12, s0l = m0 & 4095;
            #pragma unroll
            for (int rg = 0; rg < 2; ++rg)
                #pragma unroll
                for (int i = 0; i < 4; ++i) {
                    int s = s0l + rg * 16 + hi * 4 + i;
                    Vtg[((size_t)mb * Hh + col) * Ss + s] = (bf16)(acc[rg][f][i] + bvv);
                }
        } else {
            bf16* dst = (p == 0) ? Qb : Kb;
            const float scale = (p == 0) ? 0.08838834764831843f : 1.0f;
            #pragma unroll
            for (int rg = 0; rg < 2; ++rg)
                #pragma unroll
                for (int i = 0; i < 4; ++i) {
                    int row = m0 + rg * 16 + hi * 4 + i;
                    dst[(size_t)row * Hh + col] = (bf16)((acc[rg][f][i] + bvv) * scale);
                }
        }
    }
}

// ---------------------------------------------------------------------------
// Kernel 2: split-KV causal flash attention, swapped QK^T, QBLK=128,
// UNIFORM chunks: grid (CH, B); block u covers qb with nchunks(qb) =
// ceil((2qb+2)/DIV) chunks of contiguous tiles (sizes differ by <=1).
// block 256 (4 waves x 32 q-rows, 2 q-groups each).
// ---------------------------------------------------------------------------
__global__ __launch_bounds__(256, 2) void attn_kernel(
    const bf16* __restrict__ Qb, const bf16* __restrict__ Kb,
    const bf16* __restrict__ Vtg,
    float* __restrict__ Opart, float* __restrict__ Mpart, float* __restrict__ Lpart,
    int DIV, int CH)
{
    __shared__ bf16 Ks[64][136];   // K tile, stride 272B
    __shared__ bf16 Vt[128][64];   // V^T tile, (h&7)-XOR swizzled 16B chunks
    __shared__ bf16 Ps[4][32][72]; // wave-private P[q][kv], 2 q-groups

    const int t = threadIdx.x;
    const int wv = t >> 6, lane = t & 63, lo = lane & 15, hi = lane >> 4;
    const int slot = blockIdx.x, b = blockIdx.y;

    // decode slot -> (qb, chunk u of nch)
    int u = slot, qb = 0, nch = 1;
    for (qb = 0; qb < NQB; ++qb) {
        nch = (2 * qb + 2 + DIV - 1) / DIV;
        if (u < nch) break;
        u -= nch;
    }
    const int ntiles = 2 * qb + 2;
    const int t0 = (u * ntiles) / nch;
    const int t1 = ((u + 1) * ntiles) / nch;

    const int q0 = qb * QB;
    const size_t base = (size_t)b * Ss * Hh;
    const size_t vbase = (size_t)b * Hh * Ss;

    // staging pointers (rep offsets compile-time)
    const bf16* kg = Kb + base + (size_t)(t >> 4) * Hh + (t & 15) * 8;
    const bf16* vg = Vtg + vbase + (size_t)(t >> 3) * Ss + (t & 7) * 8;
    bf16* ksl = &Ks[t >> 4][(t & 15) * 8];
    bf16* vsl = &Vt[t >> 3][((t & 7) * 8) ^ (((t >> 3) & 7) << 3)];

    // Q fragments: 2 q-groups x 4 k-steps
    bf16x8 qf[2][4];
    #pragma unroll
    for (int g = 0; g < 2; ++g)
        #pragma unroll
        for (int kk = 0; kk < 4; ++kk)
            qf[g][kk] = *(const bf16x8*)(
                Qb + base + (size_t)(q0 + wv * 32 + g * 16 + lo) * Hh + kk * 32 + hi * 8);

    f32x4 acc[2][8];
    #pragma unroll
    for (int g = 0; g < 2; ++g)
        #pragma unroll
        for (int f = 0; f < 8; ++f) acc[g][f] = f32x4{0.f, 0.f, 0.f, 0.f};
    float M_[2] = {-INFINITY, -INFINITY};
    float L_[2] = {0.f, 0.f};

    uint4 kr0, kr1, kr2, kr3, vr0, vr1, vr2, vr3;
#define ISSUE(T) do {                                            \
        const bf16* kp_ = kg + (size_t)(T) * (64 * Hh);          \
        kr0 = *(const uint4*)(kp_);                              \
        kr1 = *(const uint4*)(kp_ + 16 * Hh);                    \
        kr2 = *(const uint4*)(kp_ + 32 * Hh);                    \
        kr3 = *(const uint4*)(kp_ + 48 * Hh);                    \
        const bf16* vp_ = vg + (T) * 64;                         \
        vr0 = *(const uint4*)(vp_);                              \
        vr1 = *(const uint4*)(vp_ + 32 * Ss);                    \
        vr2 = *(const uint4*)(vp_ + 64 * Ss);                    \
        vr3 = *(const uint4*)(vp_ + 96 * Ss);                    \
    } while (0)

    ISSUE(t0);
    for (int tile = t0; tile < t1; ++tile) {
        __syncthreads();   // previous tile's LDS reads done
        *(uint4*)(ksl) = kr0;
        *(uint4*)(ksl + 16 * 136) = kr1;
        *(uint4*)(ksl + 32 * 136) = kr2;
        *(uint4*)(ksl + 48 * 136) = kr3;
        *(uint4*)(vsl) = vr0;
        *(uint4*)(vsl + 32 * 64) = vr1;
        *(uint4*)(vsl + 64 * 64) = vr2;
        *(uint4*)(vsl + 96 * 64) = vr3;
        if (tile + 1 < t1) ISSUE(tile + 1);
        __syncthreads();
        const int kv0 = tile * 64;

        // S^T = K Q^T per q-group: D[kv][q], kv = f*16+hi*4+i, q = lo
        f32x4 sv[2][4];
        #pragma unroll
        for (int g = 0; g < 2; ++g)
            #pragma unroll
            for (int f = 0; f < 4; ++f) sv[g][f] = f32x4{0.f, 0.f, 0.f, 0.f};
        __builtin_amdgcn_s_setprio(1);
        #pragma unroll
        for (int kk = 0; kk < 4; ++kk) {
            #pragma unroll
            for (int f = 0; f < 4; ++f) {
                bf16x8 kf = *(const bf16x8*)&Ks[f * 16 + lo][kk * 32 + hi * 8];
                sv[0][f] = MFMA16(kf, qf[0][kk], sv[0][f]);
                sv[1][f] = MFMA16(kf, qf[1][kk], sv[1][f]);
            }
        }
        __builtin_amdgcn_s_setprio(0);

        #pragma unroll
        for (int g = 0; g < 2; ++g) {
            const int qg0 = q0 + wv * 32 + g * 16;   // wave-uniform per g
            if (kv0 + 63 > qg0) {                    // masking needed
                int qg = qg0 + lo;
                #pragma unroll
                for (int f = 0; f < 4; ++f)
                    #pragma unroll
                    for (int i = 0; i < 4; ++i)
                        if (kv0 + f * 16 + hi * 4 + i > qg) sv[g][f][i] = -INFINITY;
            }
            // online softmax: lane owns 16 kv of row q=lo; tree + 2 shuffles
            float pm = -INFINITY;
            #pragma unroll
            for (int f = 0; f < 4; ++f)
                pm = fmaxf(pm, fmaxf(fmaxf(sv[g][f][0], sv[g][f][1]),
                                     fmaxf(sv[g][f][2], sv[g][f][3])));
            pm = fmaxf(pm, __shfl_xor(pm, 16));
            pm = fmaxf(pm, __shfl_xor(pm, 32));
            float nM = fmaxf(M_[g], pm);
            float nMs = fmaxf(nM, -1e37f);           // guard fully-masked group
            float scn = __expf(M_[g] - nMs);
            float rs = 0.f;
            #pragma unroll
            for (int f = 0; f < 4; ++f)
                #pragma unroll
                for (int i = 0; i < 4; ++i) {
                    float e = __expf(sv[g][f][i] - nMs);
                    sv[g][f][i] = e;
                    rs += e;
                }
            rs += __shfl_xor(rs, 16);
            rs += __shfl_xor(rs, 32);
            L_[g] = L_[g] * scn + rs;
            M_[g] = nM;
            // rescale O: acc row q' = hi*4+i needs scn of lane lo=q' (same hi)
            #pragma unroll
            for (int i = 0; i < 4; ++i) {
                float si = __shfl(scn, (lane & 48) + hi * 4 + i);
                #pragma unroll
                for (int f = 0; f < 8; ++f) acc[g][f][i] *= si;
            }
            // P -> wave-private LDS as P[q][kv]
            #pragma unroll
            for (int f = 0; f < 4; ++f)
                #pragma unroll
                for (int i = 0; i < 4; ++i)
                    Ps[wv][g * 16 + lo][f * 16 + hi * 4 + i] = (bf16)sv[g][f][i];
        }
        // O += P V
        __builtin_amdgcn_s_setprio(1);
        #pragma unroll
        for (int kk = 0; kk < 2; ++kk) {
            bf16x8 pa0 = *(const bf16x8*)&Ps[wv][lo][kk * 32 + hi * 8];
            bf16x8 pa1 = *(const bf16x8*)&Ps[wv][16 + lo][kk * 32 + hi * 8];
            #pragma unroll
            for (int f = 0; f < 8; ++f) {
                int row = f * 16 + lo;
                bf16x8 vf = *(const bf16x8*)&Vt[row][(kk * 32 + hi * 8) ^ ((row & 7) << 3)];
                acc[0][f] = MFMA16(pa0, vf, acc[0][f]);
                acc[1][f] = MFMA16(pa1, vf, acc[1][f]);
            }
        }
        __builtin_amdgcn_s_setprio(0);
    }
#undef ISSUE
    // write unnormalized partials
    const size_t pb = ((size_t)b * CH + slot) * QB;
    #pragma unroll
    for (int g = 0; g < 2; ++g)
        #pragma unroll
        for (int f = 0; f < 8; ++f)
            #pragma unroll
            for (int i = 0; i < 4; ++i) {
                int row = wv * 32 + g * 16 + hi * 4 + i;
                Opart[(pb + row) * 128 + f * 16 + lo] = acc[g][f][i];
            }
    if (hi == 0) {
        #pragma unroll
        for (int g = 0; g < 2; ++g) {
            Mpart[pb + wv * 32 + g * 16 + lo] = M_[g];
            Lpart[pb + wv * 32 + g * 16 + lo] = L_[g];
        }
    }
}

// ---------------------------------------------------------------------------
// Kernel 3: combine chunk partials (variable chunk counts).
// grid (NQB, B), block 256.
// ---------------------------------------------------------------------------
__global__ __launch_bounds__(256) void reduce_kernel(
    const float* __restrict__ Opart, const float* __restrict__ Mpart,
    const float* __restrict__ Lpart, float* __restrict__ out, int DIV, int CH)
{
    __shared__ float wexp[7][128];
    __shared__ float invL[128];
    const int qb = blockIdx.x, b = blockIdx.y, t = threadIdx.x;
    int pbase = 0, nact = 1;
    for (int j = 0; j <= qb; ++j) {
        int n = (2 * j + 2 + DIV - 1) / DIV;
        if (j == qb) { nact = n; break; }
        pbase += n;
    }
    const size_t pb = ((size_t)b * CH + pbase) * QB;
    if (t < 128) {
        float Mstar = -INFINITY;
        for (int c = 0; c < nact; ++c) Mstar = fmaxf(Mstar, Mpart[pb + c * QB + t]);
        float Ls = 0.f;
        for (int c = 0; c < nact; ++c) {
            float wc = __expf(Mpart[pb + c * QB + t] - Mstar);
            wexp[c][t] = wc;
            Ls += wc * Lpart[pb + c * QB + t];
        }
        invL[t] = 1.f / Ls;
    }
    __syncthreads();
    #pragma unroll
    for (int rep = 0; rep < 16; ++rep) {
        int idx = rep * 256 + t;
        int row = idx >> 5, c4 = (idx & 31) * 4;
        float ox = 0.f, oy = 0.f, oz = 0.f, ow = 0.f;
        for (int c = 0; c < nact; ++c) {
            float wc = wexp[c][row];
            float4 v = *(const float4*)(Opart + (pb + (size_t)c * QB + row) * 128 + c4);
            ox += wc * v.x; oy += wc * v.y; oz += wc * v.z; ow += wc * v.w;
        }
        float il = invL[row];
        float4 o = make_float4(ox * il, oy * il, oz * il, ow * il);
        *(float4*)(out + ((size_t)b * Ss + qb * QB + row) * 128 + c4) = o;
    }
}

extern "C" void kernel_launch(void* const* d_in, const int* in_sizes, int n_in,
                              void* d_out, int out_size, void* d_ws, size_t ws_size,
                              hipStream_t stream) {
    (void)in_sizes; (void)n_in; (void)out_size;
    const float* embds = (const float*)d_in[0];
    const float* Wq = (const float*)d_in[1];
    const float* bq = (const float*)d_in[2];
    const float* Wk = (const float*)d_in[3];
    const float* bk = (const float*)d_in[4];
    const float* Wv = (const float*)d_in[5];
    const float* bv = (const float*)d_in[6];

    char* ws = (char*)d_ws;
    size_t off = 0;
    bf16* Qb  = (bf16*)(ws + off); off += (size_t)Mrows * Hh * 2;
    bf16* Kb  = (bf16*)(ws + off); off += (size_t)Mrows * Hh * 2;
    bf16* Vtg = (bf16*)(ws + off); off += (size_t)Mrows * Hh * 2;
    bf16* Wt  = (bf16*)(ws + off); off += (size_t)3 * Hh * Ee * 2;

    auto chunks_for = [](int div) {
        int s = 0;
        for (int qb = 0; qb < NQB; ++qb) s += (2 * qb + 2 + div - 1) / div;
        return s;
    };
    int DIV = 10;
    int CH = chunks_for(DIV);   // 119
    if (off + (size_t)Bb * CH * QB * 128 * 4 + (size_t)Bb * CH * QB * 8 > ws_size) {
        DIV = 20;
        CH = chunks_for(DIV);   // 68
    }
    float* Opart = (float*)(ws + off);
    size_t osz = (size_t)Bb * CH * QB * 128 * 4;
    float* Mp = (float*)(ws + off + osz);
    float* Lp = Mp + (size_t)Bb * CH * QB;

    wprep_kernel<<<dim3(Ee / 16, 3), 256, 0, stream>>>(Wq, Wk, Wv, Wt);
    proj_kernel<<<dim3(Mrows / 32), 256, 0, stream>>>(embds, Wt, bq, bk, bv, Qb, Kb, Vtg);
    attn_kernel<<<dim3(CH, Bb), 256, 0, stream>>>(Qb, Kb, Vtg, Opart, Mp, Lp, DIV, CH);
    reduce_kernel<<<dim3(NQB, Bb), 256, 0, stream>>>(Opart, Mp, Lp, (float*)d_out, DIV, CH);
}

// Round 10
// 106.047 us; speedup vs baseline: 1.1023x; 1.1023x over previous
//
#include <hip/hip_runtime.h>

typedef __bf16 bf16;
typedef __attribute__((ext_vector_type(4))) bf16 bf16x4;
typedef __attribute__((ext_vector_type(8))) bf16 bf16x8;
typedef __attribute__((ext_vector_type(4))) float f32x4;

#define MFMA16(a, b, c) __builtin_amdgcn_mfma_f32_16x16x32_bf16(a, b, c, 0, 0, 0)

#define GLDS16(gsrc, ldst) __builtin_amdgcn_global_load_lds(                   \
    (const __attribute__((address_space(1))) unsigned int*)(gsrc),             \
    (__attribute__((address_space(3))) unsigned int*)(ldst), 16, 0, 0)

constexpr int Bb = 4, Ss = 4096, Ee = 1024, Hh = 128;
constexpr int Mrows = Bb * Ss;  // 16384
constexpr int QB = 128;         // attn q-block
constexpr int NQB = Ss / QB;    // 32

// ---------------------------------------------------------------------------
// Kernel 0: W prep. Transpose W [E,H] f32 -> Wt [3][H][E] bf16.
// grid (E/16, 3), block 256.
// ---------------------------------------------------------------------------
__global__ __launch_bounds__(256) void wprep_kernel(
    const float* __restrict__ Wq, const float* __restrict__ Wk,
    const float* __restrict__ Wv, bf16* __restrict__ Wt)
{
    __shared__ bf16 Sb[16][136];
    const int w = blockIdx.y;
    const float* W = (w == 0) ? Wq : (w == 1) ? Wk : Wv;
    const int k0 = blockIdx.x * 16;
    const int t = threadIdx.x;
    {
        int r = t >> 4, cg = (t & 15) * 8;
        const float4* src = (const float4*)(W + (size_t)(k0 + r) * Hh + cg);
        float4 v0 = src[0], v1 = src[1];
        bf16x4 o0, o1;
        o0[0] = (bf16)v0.x; o0[1] = (bf16)v0.y; o0[2] = (bf16)v0.z; o0[3] = (bf16)v0.w;
        o1[0] = (bf16)v1.x; o1[1] = (bf16)v1.y; o1[2] = (bf16)v1.z; o1[3] = (bf16)v1.w;
        *(bf16x4*)&Sb[r][cg] = o0;
        *(bf16x4*)&Sb[r][cg + 4] = o1;
    }
    __syncthreads();
    {
        int h = t >> 1, kseg = (t & 1) * 8;
        bf16x8 v;
        #pragma unroll
        for (int e = 0; e < 8; ++e) v[e] = Sb[kseg + e][h];
        *(bf16x8*)&Wt[((size_t)w * Hh + h) * Ee + k0 + kseg] = v;
    }
}

// ---------------------------------------------------------------------------
// Kernel 1: fused QKV projection — round-8 structure (single-buffered
// gl_lds, both-sides swizzle, 0 measured conflicts) at 8 waves/block.
// grid (Mrows/32) = 512 (2 blocks/CU @ 56KB), block 512 = 16 waves/CU =
// 4 waves/SIMD (2x round 8's TLP). Block: 32 rows x 384 cols, BK=64.
// Per thread per k-tile: 1 A gl_lds (HBM) + 6 B gl_lds (L2-resident Wt).
// Wave wv owns col-frags F = 3wv..3wv+2 (F>>3 = proj, (F&7)*16 = col).
// V written transposed: Vtg[b][h][s]. Q pre-scaled by 1/sqrt(H).
// ---------------------------------------------------------------------------
__global__ __launch_bounds__(512, 4) void proj_kernel(
    const float* __restrict__ embds, const bf16* __restrict__ Wt,
    const float* __restrict__ bq, const float* __restrict__ bk,
    const float* __restrict__ bv,
    bf16* __restrict__ Qb, bf16* __restrict__ Kb, bf16* __restrict__ Vtg)
{
    // A: 32 rows x 256B (f32, swizzled 16B chunks)  = 8192B
    // B: 384 rows x 128B (bf16, swizzled 16B chunks) = 49152B
    __shared__ char LB[57344];

    const int t = threadIdx.x;
    const int wv = t >> 6, lane = t & 63, lo = lane & 15, hi = lane >> 4;
    const int m0 = blockIdx.x * 32;

    f32x4 acc[2][3];
    #pragma unroll
    for (int rg = 0; rg < 2; ++rg)
        #pragma unroll
        for (int f = 0; f < 3; ++f) acc[rg][f] = f32x4{0.f, 0.f, 0.f, 0.f};

    // ---- staging (per-lane swizzled source, wave-uniform linear dest) ----
    // A: wave wv stages segment wv (rows 4wv..4wv+3); lane -> row 4wv+(l>>4),
    //    LDS chunk l&15 holds source chunk (l&15)^(row&15).
    const int arow = 4 * wv + (lane >> 4);
    const float* ag = embds + (size_t)(m0 + arow) * Ee
                    + (size_t)(((lane & 15) ^ (arow & 15)) * 4);
    char* aD = LB + wv * 1024;
    // B: wave wv stages segments s = wv+8j (rows 8s..8s+7), j=0..5;
    //    lane -> row 8s+(l>>3), LDS chunk l&7 holds source chunk (l&7)^(l>>3).
    const bf16* bg = Wt + (size_t)(8 * wv + (lane >> 3)) * Ee
                   + (size_t)(((lane & 7) ^ (lane >> 3)) * 8);
    char* bD = LB + 8192 + wv * 1024;

    for (int k0 = 0; k0 < Ee; k0 += 64) {
        GLDS16(ag + k0, aD);
        #pragma unroll
        for (int j = 0; j < 6; ++j)
            GLDS16(bg + (size_t)j * (64 * Ee) + k0, bD + j * 8192);
        __syncthreads();   // drains vmcnt -> staging visible

        __builtin_amdgcn_s_setprio(1);
        #pragma unroll
        for (int kk = 0; kk < 2; ++kk) {
            // A fragments: swizzled f32 chunks -> bf16; rows lo and 16+lo
            // share sw = lo ((16+lo)&15 == lo).
            bf16x8 a0, a1;
            {
                const int p0 = (kk * 8 + 2 * hi) ^ lo;
                const char* ar = LB + lo * 256;
                float4 q0 = *(const float4*)(ar + p0 * 16);
                float4 q1 = *(const float4*)(ar + (p0 ^ 1) * 16);
                a0[0] = (bf16)q0.x; a0[1] = (bf16)q0.y; a0[2] = (bf16)q0.z; a0[3] = (bf16)q0.w;
                a0[4] = (bf16)q1.x; a0[5] = (bf16)q1.y; a0[6] = (bf16)q1.z; a0[7] = (bf16)q1.w;
                const char* ar2 = LB + (16 + lo) * 256;
                float4 r0 = *(const float4*)(ar2 + p0 * 16);
                float4 r1 = *(const float4*)(ar2 + (p0 ^ 1) * 16);
                a1[0] = (bf16)r0.x; a1[1] = (bf16)r0.y; a1[2] = (bf16)r0.z; a1[3] = (bf16)r0.w;
                a1[4] = (bf16)r1.x; a1[5] = (bf16)r1.y; a1[6] = (bf16)r1.z; a1[7] = (bf16)r1.w;
            }
            #pragma unroll
            for (int f = 0; f < 3; ++f) {
                const int brow = (wv * 3 + f) * 16 + lo;
                bf16x8 b = *(const bf16x8*)(LB + 8192 + brow * 128
                            + (((kk * 4 + hi) ^ (lo & 7)) * 16));
                acc[0][f] = MFMA16(a0, b, acc[0][f]);
                acc[1][f] = MFMA16(a1, b, acc[1][f]);
            }
        }
        __builtin_amdgcn_s_setprio(0);
        __syncthreads();   // all reads done before next stage overwrites
    }
    // epilogue: frag F -> proj/col; V transposed
    #pragma unroll
    for (int f = 0; f < 3; ++f) {
        const int F = wv * 3 + f;
        const int p = F >> 3;
        const int col = (F & 7) * 16 + lo;
        const float* bias = (p == 0) ? bq : (p == 1) ? bk : bv;
        float bvv = bias[col];
        if (p == 2) {
            const int mb = m0 >> 12, s0l = m0 & 4095;
            #pragma unroll
            for (int rg = 0; rg < 2; ++rg)
                #pragma unroll
                for (int i = 0; i < 4; ++i) {
                    int s = s0l + rg * 16 + hi * 4 + i;
                    Vtg[((size_t)mb * Hh + col) * Ss + s] = (bf16)(acc[rg][f][i] + bvv);
                }
        } else {
            bf16* dst = (p == 0) ? Qb : Kb;
            const float scale = (p == 0) ? 0.08838834764831843f : 1.0f;
            #pragma unroll
            for (int rg = 0; rg < 2; ++rg)
                #pragma unroll
                for (int i = 0; i < 4; ++i) {
                    int row = m0 + rg * 16 + hi * 4 + i;
                    dst[(size_t)row * Hh + col] = (bf16)((acc[rg][f][i] + bvv) * scale);
                }
        }
    }
}

// ---------------------------------------------------------------------------
// Kernel 2: split-KV causal flash attention, swapped QK^T, QBLK=128,
// UNIFORM chunks: grid (CH, B); block u covers qb with nchunks(qb) =
// ceil((2qb+2)/DIV) chunks of contiguous tiles (sizes differ by <=1).
// block 256 (4 waves x 32 q-rows, 2 q-groups each).
// ---------------------------------------------------------------------------
__global__ __launch_bounds__(256, 2) void attn_kernel(
    const bf16* __restrict__ Qb, const bf16* __restrict__ Kb,
    const bf16* __restrict__ Vtg,
    float* __restrict__ Opart, float* __restrict__ Mpart, float* __restrict__ Lpart,
    int DIV, int CH)
{
    __shared__ bf16 Ks[64][136];   // K tile, stride 272B
    __shared__ bf16 Vt[128][64];   // V^T tile, (h&7)-XOR swizzled 16B chunks
    __shared__ bf16 Ps[4][32][72]; // wave-private P[q][kv], 2 q-groups

    const int t = threadIdx.x;
    const int wv = t >> 6, lane = t & 63, lo = lane & 15, hi = lane >> 4;
    const int slot = blockIdx.x, b = blockIdx.y;

    // decode slot -> (qb, chunk u of nch)
    int u = slot, qb = 0, nch = 1;
    for (qb = 0; qb < NQB; ++qb) {
        nch = (2 * qb + 2 + DIV - 1) / DIV;
        if (u < nch) break;
        u -= nch;
    }
    const int ntiles = 2 * qb + 2;
    const int t0 = (u * ntiles) / nch;
    const int t1 = ((u + 1) * ntiles) / nch;

    const int q0 = qb * QB;
    const size_t base = (size_t)b * Ss * Hh;
    const size_t vbase = (size_t)b * Hh * Ss;

    // staging pointers (rep offsets compile-time)
    const bf16* kg = Kb + base + (size_t)(t >> 4) * Hh + (t & 15) * 8;
    const bf16* vg = Vtg + vbase + (size_t)(t >> 3) * Ss + (t & 7) * 8;
    bf16* ksl = &Ks[t >> 4][(t & 15) * 8];
    bf16* vsl = &Vt[t >> 3][((t & 7) * 8) ^ (((t >> 3) & 7) << 3)];

    // Q fragments: 2 q-groups x 4 k-steps
    bf16x8 qf[2][4];
    #pragma unroll
    for (int g = 0; g < 2; ++g)
        #pragma unroll
        for (int kk = 0; kk < 4; ++kk)
            qf[g][kk] = *(const bf16x8*)(
                Qb + base + (size_t)(q0 + wv * 32 + g * 16 + lo) * Hh + kk * 32 + hi * 8);

    f32x4 acc[2][8];
    #pragma unroll
    for (int g = 0; g < 2; ++g)
        #pragma unroll
        for (int f = 0; f < 8; ++f) acc[g][f] = f32x4{0.f, 0.f, 0.f, 0.f};
    float M_[2] = {-INFINITY, -INFINITY};
    float L_[2] = {0.f, 0.f};

    uint4 kr0, kr1, kr2, kr3, vr0, vr1, vr2, vr3;
#define ISSUE(T) do {                                            \
        const bf16* kp_ = kg + (size_t)(T) * (64 * Hh);          \
        kr0 = *(const uint4*)(kp_);                              \
        kr1 = *(const uint4*)(kp_ + 16 * Hh);                    \
        kr2 = *(const uint4*)(kp_ + 32 * Hh);                    \
        kr3 = *(const uint4*)(kp_ + 48 * Hh);                    \
        const bf16* vp_ = vg + (T) * 64;                         \
        vr0 = *(const uint4*)(vp_);                              \
        vr1 = *(const uint4*)(vp_ + 32 * Ss);                    \
        vr2 = *(const uint4*)(vp_ + 64 * Ss);                    \
        vr3 = *(const uint4*)(vp_ + 96 * Ss);                    \
    } while (0)

    ISSUE(t0);
    for (int tile = t0; tile < t1; ++tile) {
        __syncthreads();   // previous tile's LDS reads done
        *(uint4*)(ksl) = kr0;
        *(uint4*)(ksl + 16 * 136) = kr1;
        *(uint4*)(ksl + 32 * 136) = kr2;
        *(uint4*)(ksl + 48 * 136) = kr3;
        *(uint4*)(vsl) = vr0;
        *(uint4*)(vsl + 32 * 64) = vr1;
        *(uint4*)(vsl + 64 * 64) = vr2;
        *(uint4*)(vsl + 96 * 64) = vr3;
        if (tile + 1 < t1) ISSUE(tile + 1);
        __syncthreads();
        const int kv0 = tile * 64;

        // S^T = K Q^T per q-group: D[kv][q], kv = f*16+hi*4+i, q = lo
        f32x4 sv[2][4];
        #pragma unroll
        for (int g = 0; g < 2; ++g)
            #pragma unroll
            for (int f = 0; f < 4; ++f) sv[g][f] = f32x4{0.f, 0.f, 0.f, 0.f};
        __builtin_amdgcn_s_setprio(1);
        #pragma unroll
        for (int kk = 0; kk < 4; ++kk) {
            #pragma unroll
            for (int f = 0; f < 4; ++f) {
                bf16x8 kf = *(const bf16x8*)&Ks[f * 16 + lo][kk * 32 + hi * 8];
                sv[0][f] = MFMA16(kf, qf[0][kk], sv[0][f]);
                sv[1][f] = MFMA16(kf, qf[1][kk], sv[1][f]);
            }
        }
        __builtin_amdgcn_s_setprio(0);

        #pragma unroll
        for (int g = 0; g < 2; ++g) {
            const int qg0 = q0 + wv * 32 + g * 16;   // wave-uniform per g
            if (kv0 + 63 > qg0) {                    // masking needed
                int qg = qg0 + lo;
                #pragma unroll
                for (int f = 0; f < 4; ++f)
                    #pragma unroll
                    for (int i = 0; i < 4; ++i)
                        if (kv0 + f * 16 + hi * 4 + i > qg) sv[g][f][i] = -INFINITY;
            }
            // online softmax: lane owns 16 kv of row q=lo; tree + 2 shuffles
            float pm = -INFINITY;
            #pragma unroll
            for (int f = 0; f < 4; ++f)
                pm = fmaxf(pm, fmaxf(fmaxf(sv[g][f][0], sv[g][f][1]),
                                     fmaxf(sv[g][f][2], sv[g][f][3])));
            pm = fmaxf(pm, __shfl_xor(pm, 16));
            pm = fmaxf(pm, __shfl_xor(pm, 32));
            float nM = fmaxf(M_[g], pm);
            float nMs = fmaxf(nM, -1e37f);           // guard fully-masked group
            float scn = __expf(M_[g] - nMs);
            float rs = 0.f;
            #pragma unroll
            for (int f = 0; f < 4; ++f)
                #pragma unroll
                for (int i = 0; i < 4; ++i) {
                    float e = __expf(sv[g][f][i] - nMs);
                    sv[g][f][i] = e;
                    rs += e;
                }
            rs += __shfl_xor(rs, 16);
            rs += __shfl_xor(rs, 32);
            L_[g] = L_[g] * scn + rs;
            M_[g] = nM;
            // rescale O: acc row q' = hi*4+i needs scn of lane lo=q' (same hi)
            #pragma unroll
            for (int i = 0; i < 4; ++i) {
                float si = __shfl(scn, (lane & 48) + hi * 4 + i);
                #pragma unroll
                for (int f = 0; f < 8; ++f) acc[g][f][i] *= si;
            }
            // P -> wave-private LDS as P[q][kv]
            #pragma unroll
            for (int f = 0; f < 4; ++f)
                #pragma unroll
                for (int i = 0; i < 4; ++i)
                    Ps[wv][g * 16 + lo][f * 16 + hi * 4 + i] = (bf16)sv[g][f][i];
        }
        // O += P V
        __builtin_amdgcn_s_setprio(1);
        #pragma unroll
        for (int kk = 0; kk < 2; ++kk) {
            bf16x8 pa0 = *(const bf16x8*)&Ps[wv][lo][kk * 32 + hi * 8];
            bf16x8 pa1 = *(const bf16x8*)&Ps[wv][16 + lo][kk * 32 + hi * 8];
            #pragma unroll
            for (int f = 0; f < 8; ++f) {
                int row = f * 16 + lo;
                bf16x8 vf = *(const bf16x8*)&Vt[row][(kk * 32 + hi * 8) ^ ((row & 7) << 3)];
                acc[0][f] = MFMA16(pa0, vf, acc[0][f]);
                acc[1][f] = MFMA16(pa1, vf, acc[1][f]);
            }
        }
        __builtin_amdgcn_s_setprio(0);
    }
#undef ISSUE
    // write unnormalized partials
    const size_t pb = ((size_t)b * CH + slot) * QB;
    #pragma unroll
    for (int g = 0; g < 2; ++g)
        #pragma unroll
        for (int f = 0; f < 8; ++f)
            #pragma unroll
            for (int i = 0; i < 4; ++i) {
                int row = wv * 32 + g * 16 + hi * 4 + i;
                Opart[(pb + row) * 128 + f * 16 + lo] = acc[g][f][i];
            }
    if (hi == 0) {
        #pragma unroll
        for (int g = 0; g < 2; ++g) {
            Mpart[pb + wv * 32 + g * 16 + lo] = M_[g];
            Lpart[pb + wv * 32 + g * 16 + lo] = L_[g];
        }
    }
}

// ---------------------------------------------------------------------------
// Kernel 3: combine chunk partials (variable chunk counts).
// grid (NQB, B), block 256.
// ---------------------------------------------------------------------------
__global__ __launch_bounds__(256) void reduce_kernel(
    const float* __restrict__ Opart, const float* __restrict__ Mpart,
    const float* __restrict__ Lpart, float* __restrict__ out, int DIV, int CH)
{
    __shared__ float wexp[7][128];
    __shared__ float invL[128];
    const int qb = blockIdx.x, b = blockIdx.y, t = threadIdx.x;
    int pbase = 0, nact = 1;
    for (int j = 0; j <= qb; ++j) {
        int n = (2 * j + 2 + DIV - 1) / DIV;
        if (j == qb) { nact = n; break; }
        pbase += n;
    }
    const size_t pb = ((size_t)b * CH + pbase) * QB;
    if (t < 128) {
        float Mstar = -INFINITY;
        for (int c = 0; c < nact; ++c) Mstar = fmaxf(Mstar, Mpart[pb + c * QB + t]);
        float Ls = 0.f;
        for (int c = 0; c < nact; ++c) {
            float wc = __expf(Mpart[pb + c * QB + t] - Mstar);
            wexp[c][t] = wc;
            Ls += wc * Lpart[pb + c * QB + t];
        }
        invL[t] = 1.f / Ls;
    }
    __syncthreads();
    #pragma unroll
    for (int rep = 0; rep < 16; ++rep) {
        int idx = rep * 256 + t;
        int row = idx >> 5, c4 = (idx & 31) * 4;
        float ox = 0.f, oy = 0.f, oz = 0.f, ow = 0.f;
        for (int c = 0; c < nact; ++c) {
            float wc = wexp[c][row];
            float4 v = *(const float4*)(Opart + (pb + (size_t)c * QB + row) * 128 + c4);
            ox += wc * v.x; oy += wc * v.y; oz += wc * v.z; ow += wc * v.w;
        }
        float il = invL[row];
        float4 o = make_float4(ox * il, oy * il, oz * il, ow * il);
        *(float4*)(out + ((size_t)b * Ss + qb * QB + row) * 128 + c4) = o;
    }
}

extern "C" void kernel_launch(void* const* d_in, const int* in_sizes, int n_in,
                              void* d_out, int out_size, void* d_ws, size_t ws_size,
                              hipStream_t stream) {
    (void)in_sizes; (void)n_in; (void)out_size;
    const float* embds = (const float*)d_in[0];
    const float* Wq = (const float*)d_in[1];
    const float* bq = (const float*)d_in[2];
    const float* Wk = (const float*)d_in[3];
    const float* bk = (const float*)d_in[4];
    const float* Wv = (const float*)d_in[5];
    const float* bv = (const float*)d_in[6];

    char* ws = (char*)d_ws;
    size_t off = 0;
    bf16* Qb  = (bf16*)(ws + off); off += (size_t)Mrows * Hh * 2;
    bf16* Kb  = (bf16*)(ws + off); off += (size_t)Mrows * Hh * 2;
    bf16* Vtg = (bf16*)(ws + off); off += (size_t)Mrows * Hh * 2;
    bf16* Wt  = (bf16*)(ws + off); off += (size_t)3 * Hh * Ee * 2;

    auto chunks_for = [](int div) {
        int s = 0;
        for (int qb = 0; qb < NQB; ++qb) s += (2 * qb + 2 + div - 1) / div;
        return s;
    };
    int DIV = 10;
    int CH = chunks_for(DIV);   // 119
    if (off + (size_t)Bb * CH * QB * 128 * 4 + (size_t)Bb * CH * QB * 8 > ws_size) {
        DIV = 20;
        CH = chunks_for(DIV);   // 68
    }
    float* Opart = (float*)(ws + off);
    size_t osz = (size_t)Bb * CH * QB * 128 * 4;
    float* Mp = (float*)(ws + off + osz);
    float* Lp = Mp + (size_t)Bb * CH * QB;

    wprep_kernel<<<dim3(Ee / 16, 3), 256, 0, stream>>>(Wq, Wk, Wv, Wt);
    proj_kernel<<<dim3(Mrows / 32), 512, 0, stream>>>(embds, Wt, bq, bk, bv, Qb, Kb, Vtg);
    attn_kernel<<<dim3(CH, Bb), 256, 0, stream>>>(Qb, Kb, Vtg, Opart, Mp, Lp, DIV, CH);
    reduce_kernel<<<dim3(NQB, Bb), 256, 0, stream>>>(Opart, Mp, Lp, (float*)d_out, DIV, CH);
}